// Round 11
// baseline (214.457 us; speedup 1.0000x reference)
//
#include <hip/hip_runtime.h>
#include <float.h>
#include <math.h>

#define NV 50257
#define D 128
#define B 2048
#define C 10

#define NVPAD 50272                 // 3142 * 16
#define NTILES (NVPAD / 16)         // 3142 col-tiles of 16
#define NSTREAM 128                 // vocab streams
#define NG4 (NVPAD * D / 4)         // int (=4 fp8) count of packed W_gen
#define LOG2E 1.44269504088896f
#define SC1 0x7F7F7F7F              // e8m0 scale = 1.0 in every byte

typedef __attribute__((ext_vector_type(8))) short short8;
typedef __attribute__((ext_vector_type(8))) int int8v;
typedef __attribute__((ext_vector_type(4))) float float4v;
typedef __attribute__((ext_vector_type(2))) float float2v;

__device__ __forceinline__ float softplus_f(float x) {
    return fmaxf(x, 0.f) + log1pf(expf(-fabsf(x)));
}

__device__ __forceinline__ short f2bf(float f) {
    unsigned u = __float_as_uint(f);
    unsigned r = (u + 0x7FFFu + ((u >> 16) & 1u)) >> 16;   // RNE
    return (short)r;
}

// load 8 contiguous fp32, convert to bf16x8 fragment in-register
__device__ __forceinline__ short8 ldbf8(const float* __restrict__ p) {
    const float4 g0 = *(const float4*)p;
    const float4 g1 = *(const float4*)(p + 4);
    short8 v;
    v[0] = f2bf(g0.x); v[1] = f2bf(g0.y); v[2] = f2bf(g0.z); v[3] = f2bf(g0.w);
    v[4] = f2bf(g1.x); v[5] = f2bf(g1.y); v[6] = f2bf(g1.z); v[7] = f2bf(g1.w);
    return v;
}

// ---------------- Kernel M: fused [inference net (blocks 0..127)] + [W_gen->fp8 conv] ------
// Infer blocks: 640 thr = 10 waves, one ctx per wave; small weights loaded fp32 with
// inline bf16 cvt (k_pre eliminated). Conv blocks (bid>=128): stream-pack W_gen fp8.
#define CONVB 629                   // ceil(NG4 / (640*4))
__global__ __launch_bounds__(640) void k_main(
    const int* __restrict__ x_batch, const int* __restrict__ ctxw,
    const float* __restrict__ eps, const float* __restrict__ inf_emb,
    const float* __restrict__ waff, const float* __restrict__ b_aff,
    const float* __restrict__ wmu, const float* __restrict__ b_mu,
    const float* __restrict__ wsig, const float* __restrict__ b_sig,
    const float* __restrict__ gen_sig_emb, const float* __restrict__ wg,
    unsigned char* __restrict__ w8,
    float* __restrict__ z_out, unsigned char* __restrict__ z8_out,
    float* __restrict__ kl_out, float* __restrict__ out)
{
    const int bid = blockIdx.x;
    const int t = threadIdx.x;

    __shared__ float us[16][132];        // U tile, C-layout (8.4 KB)
    __shared__ float hsp[5][16][132];    // relu partials, 5 slabs (42.2 KB)
    __shared__ float kl_s[8][16];

    if (bid == 0 && t == 0) out[0] = 0.f;   // stream-ordered before k_final

    if (bid >= 128) {
        // ---- conversion path: 4 strided int-writes (16 fp8) per thread ----
        const int base = (bid - 128) * (640 * 4) + t;
        #pragma unroll
        for (int k = 0; k < 4; ++k) {
            const int i4 = base + k * 640;
            if (i4 < NG4) {
                const int e0 = i4 * 4;
                int pk = 0;
                if (e0 < NV * D) {
                    const float4 g = ((const float4*)wg)[i4];
                    pk = __builtin_amdgcn_cvt_pk_fp8_f32(g.x, g.y, 0, false);
                    pk = __builtin_amdgcn_cvt_pk_fp8_f32(g.z, g.w, pk, true);
                }
                ((int*)w8)[i4] = pk;
            }
        }
        return;
    }

    // ---- inference path ----
    const int b0 = bid * 16;
    const int wv = t >> 6;           // 0..9
    const int lane = t & 63;
    const int col16 = lane & 15;
    const int quad = lane >> 4;
    const int brow = b0 + col16;

    // context gather: exactly one ctx per wave
    const int widx = ctxw[brow * C + wv];
    short8 cx[4];
    #pragma unroll
    for (int ks = 0; ks < 4; ++ks)
        cx[ks] = ldbf8(inf_emb + (size_t)widx * D + ks * 32 + quad * 8);

    // U phase: wave wv (<8) computes dt-tile wv once, shares via LDS
    if (wv < 8) {
        const int cidx = x_batch[brow];
        short8 ce[4];
        #pragma unroll
        for (int ks = 0; ks < 4; ++ks)
            ce[ks] = ldbf8(inf_emb + (size_t)cidx * D + ks * 32 + quad * 8);
        float4v acc = {0.f, 0.f, 0.f, 0.f};
        #pragma unroll
        for (int ks = 0; ks < 4; ++ks) {
            const short8 bw = ldbf8(waff + (wv * 16 + col16) * 256 + ks * 32 + quad * 8);
            acc = __builtin_amdgcn_mfma_f32_16x16x32_bf16(ce[ks], bw, acc, 0, 0, 0);
        }
        #pragma unroll
        for (int r = 0; r < 4; ++r)
            us[quad * 4 + r][wv * 16 + col16] = acc[r];
    }
    __syncthreads();

    // all 10 waves: own ctx GEMM + relu into registers
    float ba[8];
    #pragma unroll
    for (int dt = 0; dt < 8; ++dt) ba[dt] = b_aff[dt * 16 + col16];

    float4v H[8];
    #pragma unroll
    for (int dt = 0; dt < 8; ++dt) {
        float4v a = {0.f, 0.f, 0.f, 0.f};
        #pragma unroll
        for (int ks = 0; ks < 4; ++ks) {
            const short8 bw = ldbf8(waff + (dt * 16 + col16) * 256 + 128 + ks * 32 + quad * 8);
            a = __builtin_amdgcn_mfma_f32_16x16x32_bf16(cx[ks], bw, a, 0, 0, 0);
        }
        #pragma unroll
        for (int r = 0; r < 4; ++r) {
            const float u = us[quad * 4 + r][dt * 16 + col16];
            H[dt][r] = fmaxf(u + a[r] + ba[dt], 0.f);
        }
    }

    // two-phase slab commit: waves 0-4 write, waves 5-9 accumulate
    if (wv < 5) {
        #pragma unroll
        for (int dt = 0; dt < 8; ++dt)
            #pragma unroll
            for (int r = 0; r < 4; ++r)
                hsp[wv][quad * 4 + r][dt * 16 + col16] = H[dt][r];
    }
    __syncthreads();
    if (wv >= 5) {
        #pragma unroll
        for (int dt = 0; dt < 8; ++dt)
            #pragma unroll
            for (int r = 0; r < 4; ++r)
                hsp[wv - 5][quad * 4 + r][dt * 16 + col16] += H[dt][r];
    }
    __syncthreads();

    // waves 0..7: sum 5 slabs -> A-frags, GEMM2 (nt=wv), epilogue
    if (wv < 8) {
        short8 ha[4];
        #pragma unroll
        for (int ks = 0; ks < 4; ++ks) {
            const int off = ks * 32 + quad * 8;
            float4 s0 = {0.f, 0.f, 0.f, 0.f}, s1 = {0.f, 0.f, 0.f, 0.f};
            #pragma unroll
            for (int w = 0; w < 5; ++w) {
                const float4 a0 = *(const float4*)&hsp[w][col16][off];
                const float4 a1 = *(const float4*)&hsp[w][col16][off + 4];
                s0.x += a0.x; s0.y += a0.y; s0.z += a0.z; s0.w += a0.w;
                s1.x += a1.x; s1.y += a1.y; s1.z += a1.z; s1.w += a1.w;
            }
            short8 v;
            v[0] = f2bf(s0.x); v[1] = f2bf(s0.y); v[2] = f2bf(s0.z); v[3] = f2bf(s0.w);
            v[4] = f2bf(s1.x); v[5] = f2bf(s1.y); v[6] = f2bf(s1.z); v[7] = f2bf(s1.w);
            ha[ks] = v;
        }

        int xb2[4];
        #pragma unroll
        for (int r = 0; r < 4; ++r) xb2[r] = x_batch[b0 + quad * 4 + r];

        const int nt = wv;
        float4v mu4 = {0.f, 0.f, 0.f, 0.f};
        float4v sg4 = {0.f, 0.f, 0.f, 0.f};
        #pragma unroll
        for (int ks = 0; ks < 4; ++ks) {
            const short8 bm = ldbf8(wmu + (nt * 16 + col16) * 128 + ks * 32 + quad * 8);
            const short8 bs = ldbf8(wsig + (nt * 16 + col16) * 128 + ks * 32 + quad * 8);
            mu4 = __builtin_amdgcn_mfma_f32_16x16x32_bf16(ha[ks], bm, mu4, 0, 0, 0);
            sg4 = __builtin_amdgcn_mfma_f32_16x16x32_bf16(ha[ks], bs, sg4, 0, 0, 0);
        }
        const int d = nt * 16 + col16;
        const float bmu = b_mu[d];
        const float bsg = b_sig[d];
        float klp[4];
        #pragma unroll
        for (int r = 0; r < 4; ++r) {
            const int b = b0 + quad * 4 + r;
            const float mu = mu4[r] + bmu;
            const float sg = sg4[r] + bsg;
            const float isig = softplus_f(sg);
            const float e = eps[b * D + d];
            const float zz = fmaf(e, isig, mu);
            z_out[b * D + d] = zz;
            const int pk = __builtin_amdgcn_cvt_pk_fp8_f32(zz * LOG2E, 0.f, 0, false);
            z8_out[b * D + d] = (unsigned char)(pk & 0xFF);
            const float gs = softplus_f(gen_sig_emb[(size_t)xb2[r] * D + d]);
            const float diff = mu - gs;
            klp[r] = logf(gs / isig) + (isig * isig + diff * diff) / (2.f * gs * gs) - 0.5f;
        }
        #pragma unroll
        for (int off = 1; off < 16; off <<= 1)
            #pragma unroll
            for (int r = 0; r < 4; ++r)
                klp[r] += __shfl_xor(klp[r], off, 64);
        if (col16 == 0) {
            #pragma unroll
            for (int r = 0; r < 4; ++r)
                kl_s[wv][quad * 4 + r] = klp[r];
        }
    }
    __syncthreads();
    if (t < 16) {
        float s = 0.f;
        #pragma unroll
        for (int w = 0; w < 8; ++w) s += kl_s[w][t];
        kl_out[b0 + t] = s;
    }
}

// ---------------- Kernel B: MX-fp8 K=128, 2 row-tiles/wave for 2x TLP ----------------
// grid 2048 = 16 row-blocks x 128 streams (XCD = s%8). Target <=64 VGPR -> 8 waves/SIMD.
#define LOADT8(bf, g, T) { \
    const int v_ = (T) < NTILES; \
    const int tt_ = v_ ? (T) : 0; \
    bf = *(const int8v*)(w8 + (size_t)(tt_ * 16 + col16) * D + quad * 32); \
    const int col_ = tt_ * 16 + col16; \
    const int cc_ = col_ < NV ? col_ : NV - 1; \
    g = (v_ && col_ < NV) ? b_gen[cc_] * LOG2E : -INFINITY; }

#define COMP8(bf, g) { \
    _Pragma("unroll") \
    for (int rt = 0; rt < 2; ++rt) { \
        float4v c = {g, g, g, g}; \
        c = __builtin_amdgcn_mfma_scale_f32_16x16x128_f8f6f4( \
                afrag[rt], bf, c, 0, 0, 0, SC1, 0, SC1); \
        _Pragma("unroll") \
        for (int r = 0; r < 4; ++r) \
            sums[rt][r] += __builtin_amdgcn_exp2f(c[r]); \
    } }

__global__ __launch_bounds__(256) void k_lse_mfma(
    const unsigned char* __restrict__ z8, const unsigned char* __restrict__ w8,
    const float* __restrict__ b_gen, float* __restrict__ part_s)
{
    const int bid = blockIdx.x;
    const int s = bid & 127;                        // stream; XCD = s%8
    const int x = bid >> 7;                         // row block (128 rows)
    const int t = threadIdx.x;
    const int wv = t >> 6;
    const int lane = t & 63;
    const int col16 = lane & 15;
    const int quad = lane >> 4;
    const int rowbase = x * 128 + wv * 32;

    int8v afrag[2];
    #pragma unroll
    for (int rt = 0; rt < 2; ++rt)
        afrag[rt] = *(const int8v*)(z8 + (size_t)(rowbase + rt * 16 + col16) * D + quad * 32);

    float sums[2][4];
    #pragma unroll
    for (int rt = 0; rt < 2; ++rt)
        #pragma unroll
        for (int r = 0; r < 4; ++r) sums[rt][r] = 0.f;

    // exactly 25 tiles (streams s>=70 have 24; only the last is clamped -> -inf).
    int8v bA, bB;
    float gA, gB;
    LOADT8(bA, gA, s);
    #pragma unroll 1
    for (int j = 0; j < 12; ++j) {
        LOADT8(bB, gB, s + (2 * j + 1) * 128);
        COMP8(bA, gA);
        LOADT8(bA, gA, s + (2 * j + 2) * 128);
        COMP8(bB, gB);
    }
    COMP8(bA, gA);                                  // tile 24 (clamped for s>=70)

    #pragma unroll
    for (int off = 1; off < 16; off <<= 1)
        #pragma unroll
        for (int rt = 0; rt < 2; ++rt)
            #pragma unroll
            for (int r = 0; r < 4; ++r)
                sums[rt][r] += __shfl_xor(sums[rt][r], off, 64);

    if (col16 == 0) {
        #pragma unroll
        for (int rt = 0; rt < 2; ++rt)
            #pragma unroll
            for (int r = 0; r < 4; ++r) {
                const int row = rowbase + rt * 16 + quad * 4 + r;
                part_s[row * NSTREAM + s] = sums[rt][r];
            }
    }
}

// ---------------- Kernel C: finalize (fp8 ctx gather, L2-hot), one atomic/block ----------------
__global__ __launch_bounds__(256) void k_final(
    const float* __restrict__ z, const unsigned char* __restrict__ w8,
    const float* __restrict__ b_gen, const int* __restrict__ ctxw,
    const float* __restrict__ part_s, const float* __restrict__ kl,
    float* __restrict__ out)
{
    const int t = threadIdx.x;
    const int wv = t >> 6;
    const int lane = t & 63;
    __shared__ float red[4];

    float wsum = 0.f;
    #pragma unroll
    for (int rr = 0; rr < 2; ++rr) {
        const int b = blockIdx.x * 8 + wv * 2 + rr;

        int idxs[C];
        #pragma unroll
        for (int c = 0; c < C; ++c) idxs[c] = ctxw[b * C + c];
        unsigned short uw[C];
        #pragma unroll
        for (int c = 0; c < C; ++c)
            uw[c] = *(const unsigned short*)(w8 + (size_t)idxs[c] * D + lane * 2);
        float sum_bg = 0.f;
        #pragma unroll
        for (int c = 0; c < C; ++c) sum_bg += b_gen[idxs[c]];

        float sv = part_s[b * NSTREAM + lane] + part_s[b * NSTREAM + 64 + lane];
        const float z0 = z[b * D + lane * 2];
        const float z1 = z[b * D + lane * 2 + 1];

        float acc = 0.f;
        #pragma unroll
        for (int c = 0; c < C; ++c) {
            const float2v wf = __builtin_amdgcn_cvt_pk_f32_fp8((int)uw[c], false);
            acc = fmaf(z0, wf[0], acc);
            acc = fmaf(z1, wf[1], acc);
        }
        #pragma unroll
        for (int off = 32; off > 0; off >>= 1) {
            sv  += __shfl_xor(sv, off, 64);
            acc += __shfl_xor(acc, off, 64);
        }
        if (lane == 0) {
            const float lse = logf(sv);
            const float recon = acc + sum_bg - C * lse;
            wsum += kl[b] - recon;
        }
    }
    if (lane == 0) red[wv] = wsum;
    __syncthreads();
    if (t == 0) atomicAdd(out, (red[0] + red[1] + red[2] + red[3]) * (1.f / B));
}

extern "C" void kernel_launch(void* const* d_in, const int* in_sizes, int n_in,
                              void* d_out, int out_size, void* d_ws, size_t ws_size,
                              hipStream_t stream) {
    const int* x_batch = (const int*)d_in[0];
    const int* ctxw    = (const int*)d_in[1];
    const float* eps   = (const float*)d_in[2];
    const float* inf_emb = (const float*)d_in[3];
    const float* W_aff = (const float*)d_in[4];
    const float* b_aff = (const float*)d_in[5];
    const float* W_mu  = (const float*)d_in[6];
    const float* b_mu  = (const float*)d_in[7];
    const float* W_sig = (const float*)d_in[8];
    const float* b_sig = (const float*)d_in[9];
    const float* gen_sig = (const float*)d_in[10];
    const float* W_gen = (const float*)d_in[11];
    const float* b_gen = (const float*)d_in[12];
    float* out = (float*)d_out;

    char* ws = (char*)d_ws;
    float* z      = (float*)ws;   ws += (size_t)B * D * 4;
    float* part_s = (float*)ws;   ws += (size_t)B * NSTREAM * 4;
    float* kl     = (float*)ws;   ws += (size_t)B * 4;
    unsigned char* z8 = (unsigned char*)ws;  ws += (size_t)B * D;
    unsigned char* w8 = (unsigned char*)ws;  ws += (size_t)NVPAD * D;

    hipLaunchKernelGGL(k_main, dim3(128 + CONVB), dim3(640), 0, stream,
                       x_batch, ctxw, eps, inf_emb, W_aff, b_aff, W_mu, b_mu,
                       W_sig, b_sig, gen_sig, W_gen, w8, z, z8, kl, out);
    hipLaunchKernelGGL(k_lse_mfma, dim3(16 * NSTREAM), dim3(256), 0, stream,
                       z8, w8, b_gen, part_s);
    hipLaunchKernelGGL(k_final, dim3(B / 8), dim3(256), 0, stream,
                       z, w8, b_gen, ctxw, part_s, kl, out);
}